// Round 1
// baseline (40733.066 us; speedup 1.0000x reference)
//
#include <hip/hip_runtime.h>
#include <math.h>

// EchoStateNetwork: B=32, S=4096, I=64, R=1024, O=8, fp32.
// Persistent kernel: 16 chain-pairs x 16 WGs = 256 WGs (1/CU).
// Each WG holds 64 rows of W_res (for both chains of its pair) in VGPRs
// (128 f32/thread), W_in/W_out slices in LDS. Per step: load r_{t-1} slice
// from global exchange buffer -> LDS, dot in registers, tanh, store slice,
// group barrier via agent-scope atomic counter. Output GEMM fused via
// per-WG partials + rotating reducer.

#define NB 32
#define NS 4096
#define NI 64
#define NR 1024
#define NO 8
#define NPAIR 16
#define GPP 16      // WGs per pair group
#define ROWS 64     // W_res rows per WG
#define NT 512      // threads per WG (8 waves)

__global__ void init_cnt_kernel(unsigned int* cnt) {
  cnt[threadIdx.x] = 0u;   // 1024 threads zero 4 KB of counters
}

__global__ __launch_bounds__(NT, 2) void esn_scan(
    const float* __restrict__ x, const float* __restrict__ Win,
    const float* __restrict__ Wres, const float* __restrict__ Wout,
    float* __restrict__ out, unsigned int* __restrict__ cnt,
    float* __restrict__ rbuf, float* __restrict__ pbuf)
{
  const int wg  = blockIdx.x;
  const int p   = wg >> 4;      // pair 0..15
  const int g   = wg & 15;      // member 0..15
  const int tid = threadIdx.x;
  const int w   = tid >> 6;     // wave 0..7
  const int l   = tid & 63;     // lane
  const int row = ROWS * g + l; // this lane's W_res row (all waves share rows via col split)
  const int c0  = 2 * p, c1 = 2 * p + 1;

  __shared__ float r_lds[2][NR];        // r_{t-1} for both chains
  __shared__ float x_lds[2][2][NI];     // [t parity][chain][i]
  __shared__ float part[2][8][64];      // per-wave dot partials
  __shared__ float win_s[ROWS][NI + 1]; // W_in rows slice (padded)
  __shared__ float woutr_s[NO][ROWS];   // W_out r-part own cols
  __shared__ float woutx_s[NO][NI];     // W_out x-part (all WGs, for reducer role)

  // ---- startup: weights into registers / LDS ----
  float wreg[128];  // W_res[row][128w .. 128w+127]
  {
    const float* wp_ = Wres + (size_t)row * NR + 128 * w;
    #pragma unroll
    for (int j = 0; j < 128; ++j) wreg[j] = wp_[j];
  }
  for (int idx = tid; idx < ROWS * NI; idx += NT) {
    int rr = idx >> 6, ii = idx & 63;
    win_s[rr][ii] = Win[(ROWS * g + rr) * NI + ii];
  }
  for (int idx = tid; idx < NO * ROWS; idx += NT) {
    int o = idx >> 6, cc = idx & 63;
    woutr_s[o][cc] = Wout[o * (NI + NR) + NI + ROWS * g + cc];
  }
  for (int idx = tid; idx < NO * NI; idx += NT) {
    int o = idx >> 6, ii = idx & 63;
    woutx_s[o][ii] = Wout[o * (NI + NR) + ii];
  }
  for (int idx = tid; idx < 2 * NR; idx += NT) ((float*)r_lds)[idx] = 0.f;
  __syncthreads();

  unsigned int* mycnt = cnt + p * 64;  // 256 B apart per pair

  for (int t = 0; t < NS; ++t) {
    // ---- Phase L: fetch r_{t-1} slice (wave w: cols [128w,128w+128)) + x_t ----
    if (t > 0) {
      const float* rb = rbuf + (size_t)((t - 1) & 1) * NB * NR;
      int cb = 128 * w + 2 * l;
      float2 v0 = *(const float2*)(rb + (size_t)c0 * NR + cb);
      float2 v1 = *(const float2*)(rb + (size_t)c1 * NR + cb);
      *(float2*)&r_lds[0][cb] = v0;
      *(float2*)&r_lds[1][cb] = v1;
    }
    if (w < 2) {
      x_lds[t & 1][w][l] = x[((size_t)(c0 + w) * NS + t) * NI + l];
    }
    // ---- rotating reducer: finalize out[., t-1, .] from step t-1 partials ----
    if (t > 0 && g == ((t - 1) & 15) && w == 7 && l < 16) {
      int c = l >> 3, o = l & 7;
      const float* pb = pbuf + (size_t)((t - 1) & 1) * NB * GPP * NO;
      float s = 0.f;
      #pragma unroll
      for (int gp = 0; gp < GPP; ++gp)
        s += pb[((size_t)(c0 + c) * GPP + gp) * NO + o];
      #pragma unroll
      for (int ii = 0; ii < NI; ++ii)
        s += woutx_s[o][ii] * x_lds[(t - 1) & 1][c][ii];
      out[((size_t)(c0 + c) * NS + (t - 1)) * NO + o] = s;
    }
    __syncthreads();

    // ---- Phase C: register-resident dot (8 independent FMA chains) ----
    float a0 = 0.f, a1 = 0.f, a2 = 0.f, a3 = 0.f;
    float b0 = 0.f, b1 = 0.f, b2 = 0.f, b3 = 0.f;
    {
      const float4* r0p = (const float4*)&r_lds[0][128 * w];
      const float4* r1p = (const float4*)&r_lds[1][128 * w];
      #pragma unroll
      for (int j = 0; j < 32; ++j) {
        float4 ra = r0p[j];
        float4 rb4 = r1p[j];
        a0 = fmaf(wreg[4 * j + 0], ra.x, a0);
        a1 = fmaf(wreg[4 * j + 1], ra.y, a1);
        a2 = fmaf(wreg[4 * j + 2], ra.z, a2);
        a3 = fmaf(wreg[4 * j + 3], ra.w, a3);
        b0 = fmaf(wreg[4 * j + 0], rb4.x, b0);
        b1 = fmaf(wreg[4 * j + 1], rb4.y, b1);
        b2 = fmaf(wreg[4 * j + 2], rb4.z, b2);
        b3 = fmaf(wreg[4 * j + 3], rb4.w, b3);
      }
    }
    part[0][w][l] = (a0 + a1) + (a2 + a3);
    part[1][w][l] = (b0 + b1) + (b2 + b3);
    __syncthreads();

    // ---- epilogue: waves 0,1 finish their chain's 64 rows ----
    if (w < 2) {
      const int c = w;
      float sum = 0.f;
      #pragma unroll
      for (int wp2 = 0; wp2 < 8; ++wp2) sum += part[c][wp2][l];
      float pin = 0.f;
      #pragma unroll
      for (int ii = 0; ii < NI; ++ii)
        pin = fmaf(win_s[l][ii], x_lds[t & 1][c][ii], pin);
      float rv = tanhf(sum + pin);
      rbuf[(size_t)(t & 1) * NB * NR + (size_t)(c0 + c) * NR + row] = rv;
      // W_out partials for this WG's 64 features
      float my = 0.f;
      #pragma unroll
      for (int o = 0; o < NO; ++o) {
        float v = rv * woutr_s[o][l];
        v += __shfl_xor(v, 1);
        v += __shfl_xor(v, 2);
        v += __shfl_xor(v, 4);
        v += __shfl_xor(v, 8);
        v += __shfl_xor(v, 16);
        v += __shfl_xor(v, 32);
        if (l == o) my = v;
      }
      if (l < NO)
        pbuf[(size_t)(t & 1) * NB * GPP * NO + ((size_t)(c0 + c) * GPP + g) * NO + l] = my;
    }

    // ---- group barrier (16 WGs of this pair) ----
    __syncthreads();  // compiler drains vmcnt before s_barrier -> all stores issued
    if (tid == 0) {
      __hip_atomic_fetch_add(mycnt, 1u, __ATOMIC_RELEASE, __HIP_MEMORY_SCOPE_AGENT);
      const unsigned int target = (unsigned int)(GPP * (t + 1));
      while (__hip_atomic_load(mycnt, __ATOMIC_ACQUIRE, __HIP_MEMORY_SCOPE_AGENT) < target) { }
    }
    __syncthreads();
  }

  // ---- final reduction for t = NS-1 ----
  if (g == ((NS - 1) & 15) && w == 7 && l < 16) {
    int c = l >> 3, o = l & 7;
    const float* pb = pbuf + (size_t)((NS - 1) & 1) * NB * GPP * NO;
    float s = 0.f;
    #pragma unroll
    for (int gp = 0; gp < GPP; ++gp)
      s += pb[((size_t)(c0 + c) * GPP + gp) * NO + o];
    #pragma unroll
    for (int ii = 0; ii < NI; ++ii)
      s += woutx_s[o][ii] * x_lds[(NS - 1) & 1][c][ii];
    out[((size_t)(c0 + c) * NS + (NS - 1)) * NO + o] = s;
  }
}

extern "C" void kernel_launch(void* const* d_in, const int* in_sizes, int n_in,
                              void* d_out, int out_size, void* d_ws, size_t ws_size,
                              hipStream_t stream) {
  const float* x    = (const float*)d_in[0];
  const float* Win  = (const float*)d_in[1];
  const float* Wres = (const float*)d_in[2];
  const float* Wout = (const float*)d_in[3];
  float* out = (float*)d_out;

  char* ws = (char*)d_ws;
  unsigned int* cnt = (unsigned int*)ws;                       // 4 KB (16 pairs x 256 B)
  float* rbuf = (float*)(ws + 4096);                           // 2*32*1024*4 = 256 KB
  float* pbuf = (float*)(ws + 4096 + 2 * NB * NR * 4);         // 2*32*16*8*4 = 32 KB

  hipLaunchKernelGGL(init_cnt_kernel, dim3(1), dim3(1024), 0, stream, cnt);
  hipLaunchKernelGGL(esn_scan, dim3(256), dim3(NT), 0, stream,
                     x, Win, Wres, Wout, out, cnt, rbuf, pbuf);
}